// Round 1
// baseline (382.073 us; speedup 1.0000x reference)
//
#include <hip/hip_runtime.h>

// Problem constants
#define EMB   1536
#define RANK  32
#define RANK2 1024   // RANK*RANK
#define N3    204
#define N10   34
#define D3    3840
#define D10   10240

// ---------------------------------------------------------------------------
// Kernel 1: batched GEMV  P[row] = dot(W[row, 0:1536], x) + b[row]
// One wave (64 lanes) per output row. Row is contiguous 1536 f32 -> 6 float4
// loads per lane, fully coalesced. x (6 KB) stays resident in L1/L2.
// ---------------------------------------------------------------------------
__global__ void gemv_kernel(const float* __restrict__ W,
                            const float* __restrict__ b,
                            const float* __restrict__ x,
                            float* __restrict__ P,
                            int total_rows) {
    const int wavesPerBlock = blockDim.x >> 6;
    const int row  = blockIdx.x * wavesPerBlock + (threadIdx.x >> 6);
    const int lane = threadIdx.x & 63;
    if (row >= total_rows) return;

    const float* w = W + (size_t)row * EMB;
    float acc = 0.f;
#pragma unroll
    for (int it = 0; it < EMB / 256; ++it) {      // 1536 / (64 lanes * 4) = 6
        const int e = (it * 64 + lane) * 4;
        const float4 wv = *reinterpret_cast<const float4*>(w + e);
        const float4 xv = *reinterpret_cast<const float4*>(x + e);
        acc = fmaf(wv.x, xv.x, acc);
        acc = fmaf(wv.y, xv.y, acc);
        acc = fmaf(wv.z, xv.z, acc);
        acc = fmaf(wv.w, xv.w, acc);
    }
    // wave-64 reduction
#pragma unroll
    for (int off = 32; off > 0; off >>= 1)
        acc += __shfl_down(acc, off);
    if (lane == 0) P[row] = acc + b[row];
}

// ---------------------------------------------------------------------------
// Kernel 2: per-module  la[i, d] = sum_j P[i, j] * A[j, d]   (P is 32x32)
// One thread per output column d. P staged in LDS (reads are wave-uniform
// broadcasts -> conflict-free). A[j, d] reads coalesced across threads (d
// contiguous). Each thread emits 32 outputs, each write coalesced.
// ---------------------------------------------------------------------------
__global__ void pa_kernel(const float* __restrict__ P,
                          const float* __restrict__ A,
                          float* __restrict__ out,
                          int D, int blocksPerModule) {
    const int module = blockIdx.x / blocksPerModule;
    const int dblk   = blockIdx.x % blocksPerModule;
    const int d      = dblk * blockDim.x + threadIdx.x;

    __shared__ float Ps[RANK2];
    for (int i = threadIdx.x; i < RANK2; i += blockDim.x)
        Ps[i] = P[(size_t)module * RANK2 + i];
    __syncthreads();

    if (d >= D) return;

    const float* a = A + (size_t)module * RANK * D + d;
    float av[RANK];
#pragma unroll
    for (int j = 0; j < RANK; ++j)
        av[j] = a[(size_t)j * D];

    float* o = out + (size_t)module * RANK * D + d;
#pragma unroll
    for (int i = 0; i < RANK; ++i) {
        float acc = 0.f;
#pragma unroll
        for (int j = 0; j < RANK; ++j)
            acc = fmaf(Ps[i * RANK + j], av[j], acc);
        o[(size_t)i * D] = acc;
    }
}

// ---------------------------------------------------------------------------
// Launch
// Inputs (setup_inputs order): x, Wp3, bp3, Wp10, bp10, A3, A10, B3, B10
// Output layout (flat concat): la3 | la10 | B3 | B10
// ---------------------------------------------------------------------------
extern "C" void kernel_launch(void* const* d_in, const int* in_sizes, int n_in,
                              void* d_out, int out_size, void* d_ws, size_t ws_size,
                              hipStream_t stream) {
    const float* x    = (const float*)d_in[0];
    const float* Wp3  = (const float*)d_in[1];
    const float* bp3  = (const float*)d_in[2];
    const float* Wp10 = (const float*)d_in[3];
    const float* bp10 = (const float*)d_in[4];
    const float* A3   = (const float*)d_in[5];
    const float* A10  = (const float*)d_in[6];
    const float* B3   = (const float*)d_in[7];
    const float* B10  = (const float*)d_in[8];

    float* out = (float*)d_out;

    // workspace: P3 (204*1024 f32) then P10 (34*1024 f32) = ~975 KB
    float* P3  = (float*)d_ws;
    float* P10 = P3 + (size_t)N3 * RANK2;

    const size_t SZ_LA3  = (size_t)N3  * RANK * D3;   // 25,067,520
    const size_t SZ_LA10 = (size_t)N10 * RANK * D10;  // 11,141,120

    float* la3  = out;
    float* la10 = out + SZ_LA3;
    float* oB3  = la10 + SZ_LA10;
    float* oB10 = oB3 + SZ_LA3;   // B3 has same element count as la3

    // Phase 1: GEMVs (4 waves / 256-thread block -> 4 rows per block)
    {
        const int rows3 = N3 * RANK2;           // 208,896
        const int rows10 = N10 * RANK2;         // 34,816
        gemv_kernel<<<rows3 / 4, 256, 0, stream>>>(Wp3, bp3, x, P3, rows3);
        gemv_kernel<<<rows10 / 4, 256, 0, stream>>>(Wp10, bp10, x, P10, rows10);
    }

    // Phase 2: P @ A
    {
        const int bpm3  = D3 / 256;    // 15
        const int bpm10 = D10 / 256;   // 40
        pa_kernel<<<N3 * bpm3, 256, 0, stream>>>(P3, A3, la3, D3, bpm3);
        pa_kernel<<<N10 * bpm10, 256, 0, stream>>>(P10, A10, la10, D10, bpm10);
    }

    // Phase 3: pass-through copies of B3, B10
    hipMemcpyAsync(oB3,  B3,  SZ_LA3  * sizeof(float), hipMemcpyDeviceToDevice, stream);
    hipMemcpyAsync(oB10, B10, SZ_LA10 * sizeof(float), hipMemcpyDeviceToDevice, stream);
}

// Round 2
// 367.575 us; speedup vs baseline: 1.0394x; 1.0394x over previous
//
#include <hip/hip_runtime.h>

// Problem constants
#define EMB   1536
#define RANK  32
#define RANK2 1024   // RANK*RANK
#define N3    204
#define N10   34
#define D3    3840
#define D10   10240

#define ROWS3  (N3 * RANK2)    // 208896
#define ROWS10 (N10 * RANK2)   //  34816

#define BPM3   (D3 / 256)      // 15 blocks per module (pa3)
#define BPM10  (D10 / 256)     // 40 blocks per module (pa10)
#define PA3_BLOCKS  (N3 * BPM3)    // 3060
#define PA10_BLOCKS (N10 * BPM10)  // 1360

#define SZ_LA3  ((size_t)N3  * RANK * D3)    // 25,067,520 floats
#define SZ_LA10 ((size_t)N10 * RANK * D10)   // 11,141,120 floats

// copy granularity: 4096 float4 (=16384 floats) per 256-thread block
#define CP_F4_PER_BLOCK 4096
#define CP3_BLOCKS  ((int)(SZ_LA3  / 4 / CP_F4_PER_BLOCK))  // 1530
#define CP10_BLOCKS ((int)(SZ_LA10 / 4 / CP_F4_PER_BLOCK))  // 680

// ---------------------------------------------------------------------------
// Kernel 1: both GEMV groups. One wave per output row:
//   P[row] = dot(W[row, 0:1536], x) + b[row]
// Row is contiguous 1536 f32 -> 6 float4 loads/lane, fully coalesced.
// ---------------------------------------------------------------------------
__global__ void gemv_all(const float* __restrict__ W3,
                         const float* __restrict__ b3,
                         const float* __restrict__ W10,
                         const float* __restrict__ b10,
                         const float* __restrict__ x,
                         float* __restrict__ P3,
                         float* __restrict__ P10) {
    const int wave = blockIdx.x * (blockDim.x >> 6) + (threadIdx.x >> 6);
    const int lane = threadIdx.x & 63;

    const float* W;
    const float* b;
    float* P;
    int row;
    if (wave < ROWS3) {
        W = W3; b = b3; P = P3; row = wave;
    } else {
        W = W10; b = b10; P = P10; row = wave - ROWS3;
    }

    const float* w = W + (size_t)row * EMB;
    float acc = 0.f;
#pragma unroll
    for (int it = 0; it < EMB / 256; ++it) {      // 6 iterations
        const int e = (it * 64 + lane) * 4;
        const float4 wv = *reinterpret_cast<const float4*>(w + e);
        const float4 xv = *reinterpret_cast<const float4*>(x + e);
        acc = fmaf(wv.x, xv.x, acc);
        acc = fmaf(wv.y, xv.y, acc);
        acc = fmaf(wv.z, xv.z, acc);
        acc = fmaf(wv.w, xv.w, acc);
    }
#pragma unroll
    for (int off = 32; off > 0; off >>= 1)
        acc += __shfl_down(acc, off);
    if (lane == 0) P[row] = acc + b[row];
}

// ---------------------------------------------------------------------------
// Kernel 2: pa3 + pa10 + B3/B10 pass-through copy, one grid.
// Block-uniform branch on blockIdx range.
// ---------------------------------------------------------------------------
__device__ __forceinline__ void pa_block(const float* __restrict__ P,
                                         const float* __restrict__ A,
                                         float* __restrict__ out,
                                         int module, int dblk, int D) {
    __shared__ float Ps[RANK2];
    for (int i = threadIdx.x; i < RANK2; i += blockDim.x)
        Ps[i] = P[(size_t)module * RANK2 + i];
    __syncthreads();

    const int d = dblk * blockDim.x + threadIdx.x;   // D % 256 == 0, always valid
    const float* a = A + (size_t)module * RANK * D + d;
    float av[RANK];
#pragma unroll
    for (int j = 0; j < RANK; ++j)
        av[j] = a[(size_t)j * D];

    float* o = out + (size_t)module * RANK * D + d;
#pragma unroll
    for (int i = 0; i < RANK; ++i) {
        float acc = 0.f;
#pragma unroll
        for (int j = 0; j < RANK; ++j)
            acc = fmaf(Ps[i * RANK + j], av[j], acc);
        o[(size_t)i * D] = acc;
    }
}

__device__ __forceinline__ void copy_block(const float4* __restrict__ src,
                                           float4* __restrict__ dst,
                                           int chunk) {
    const size_t base = (size_t)chunk * CP_F4_PER_BLOCK + threadIdx.x;
#pragma unroll
    for (int it = 0; it < CP_F4_PER_BLOCK / 256; ++it)   // 16 iterations
        dst[base + it * 256] = src[base + it * 256];
}

__global__ void fused_b(const float* __restrict__ P3,
                        const float* __restrict__ A3,
                        float* __restrict__ la3,
                        const float* __restrict__ P10,
                        const float* __restrict__ A10,
                        float* __restrict__ la10,
                        const float4* __restrict__ B3,
                        float4* __restrict__ oB3,
                        const float4* __restrict__ B10,
                        float4* __restrict__ oB10) {
    int bid = blockIdx.x;
    if (bid < PA3_BLOCKS) {
        pa_block(P3, A3, la3, bid / BPM3, bid % BPM3, D3);
        return;
    }
    bid -= PA3_BLOCKS;
    if (bid < PA10_BLOCKS) {
        pa_block(P10, A10, la10, bid / BPM10, bid % BPM10, D10);
        return;
    }
    bid -= PA10_BLOCKS;
    if (bid < CP3_BLOCKS) {
        copy_block(B3, oB3, bid);
        return;
    }
    bid -= CP3_BLOCKS;
    copy_block(B10, oB10, bid);
}

// ---------------------------------------------------------------------------
// Launch
// Inputs (setup_inputs order): x, Wp3, bp3, Wp10, bp10, A3, A10, B3, B10
// Output layout (flat concat): la3 | la10 | B3 | B10
// ---------------------------------------------------------------------------
extern "C" void kernel_launch(void* const* d_in, const int* in_sizes, int n_in,
                              void* d_out, int out_size, void* d_ws, size_t ws_size,
                              hipStream_t stream) {
    const float* x    = (const float*)d_in[0];
    const float* Wp3  = (const float*)d_in[1];
    const float* bp3  = (const float*)d_in[2];
    const float* Wp10 = (const float*)d_in[3];
    const float* bp10 = (const float*)d_in[4];
    const float* A3   = (const float*)d_in[5];
    const float* A10  = (const float*)d_in[6];
    const float* B3   = (const float*)d_in[7];
    const float* B10  = (const float*)d_in[8];

    float* out = (float*)d_out;

    // workspace: P3 (204*1024 f32) then P10 (34*1024 f32)
    float* P3  = (float*)d_ws;
    float* P10 = P3 + (size_t)N3 * RANK2;

    float* la3  = out;
    float* la10 = out + SZ_LA3;
    float* oB3  = la10 + SZ_LA10;
    float* oB10 = oB3 + SZ_LA3;

    // Phase 1: all GEMVs, one launch (4 waves / 256-thread block)
    gemv_all<<<(ROWS3 + ROWS10) / 4, 256, 0, stream>>>(
        Wp3, bp3, Wp10, bp10, x, P3, P10);

    // Phase 2: pa3 + pa10 + B copies, one launch
    const int total_blocks = PA3_BLOCKS + PA10_BLOCKS + CP3_BLOCKS + CP10_BLOCKS;
    fused_b<<<total_blocks, 256, 0, stream>>>(
        P3, A3, la3, P10, A10, la10,
        (const float4*)B3, (float4*)oB3,
        (const float4*)B10, (float4*)oB10);
}